// Round 1
// baseline (509.486 us; speedup 1.0000x reference)
//
#include <hip/hip_runtime.h>
#include <stdint.h>

typedef __bf16 bf16x8 __attribute__((ext_vector_type(8)));
typedef float f32x4 __attribute__((ext_vector_type(4)));
typedef unsigned short ushort_t;

#define NPARENT 60000
#define NOUT (NPARENT*8)          // 480000 output rows
#define ZIDX NOUT                 // zero row index (missing neighbors)
#define TBL_N (66*66*66)          // parent table, coords shifted +1 (range [-1,64])

static constexpr size_t OFF_TABLE = 0;
static constexpr size_t OFF_Y     = 1152000;                                // > TBL_N*4, 128-aligned
static constexpr size_t OFF_Z     = OFF_Y + (size_t)(NOUT+1)*128;
static constexpr size_t OFF_FEATB = OFF_Z + (size_t)(NOUT+1)*128;
static constexpr size_t OFF_WUPF  = OFF_FEATB + (size_t)NPARENT*128;
static constexpr size_t OFF_W1F   = OFF_WUPF + (size_t)8*8192;
static constexpr size_t OFF_W2F   = OFF_W1F + (size_t)27*8192;
static constexpr size_t WS_NEED   = OFF_W2F + (size_t)27*8192;              // ~132 MB

__device__ __forceinline__ ushort_t f2bf(float x) {   // RNE float->bf16
  uint32_t u = __float_as_uint(x);
  u += 0x7fffu + ((u >> 16) & 1u);
  return (ushort_t)(u >> 16);
}

__global__ void k_zero(ushort_t* y, ushort_t* z) {
  int t = threadIdx.x;
  if (t < 64) y[(size_t)ZIDX*64 + t] = 0;
  else        z[(size_t)ZIDX*64 + (t-64)] = 0;
}

__global__ void k_table(const int* __restrict__ coords, int* __restrict__ tbl) {
  int i = blockIdx.x*blockDim.x + threadIdx.x;
  if (i >= NPARENT) return;
  int x = coords[3*i], y = coords[3*i+1], z = coords[3*i+2];
  tbl[((x+1)*66 + (y+1))*66 + (z+1)] = i;
}

__global__ void k_feats_bf16(const float4* __restrict__ f, ushort_t* __restrict__ o, int n4) {
  int i = blockIdx.x*blockDim.x + threadIdx.x;
  if (i >= n4) return;
  float4 v = f[i];
  o[4*i+0] = f2bf(v.x); o[4*i+1] = f2bf(v.y);
  o[4*i+2] = f2bf(v.z); o[4*i+3] = f2bf(v.w);
}

// W[k][c][d] f32 -> bf16 in MFMA B-fragment order:
// frag f = ks*4+nt (ks = c>>5, nt = d>>4), lane = ((c>>3)&3)*16 + (d&15), elem e = c&7
// byte offset = (k*8+f)*1024 + lane*16 + e*2  -> wave frag load is 1KB contiguous.
__global__ void k_wfrag(const float* __restrict__ w, ushort_t* __restrict__ o, int total) {
  int i = blockIdx.x*blockDim.x + threadIdx.x;
  if (i >= total) return;
  int k = i >> 12, r = i & 4095, c = r >> 6, d = r & 63;
  int nt = d >> 4, lp = d & 15, ks = c >> 5, hi = (c >> 3) & 3, e = c & 7;
  int fi = ks*4 + nt, lane = hi*16 + lp;
  o[(size_t)(k*8 + fi)*512 + lane*8 + e] = f2bf(w[i]);
}

// up-projection: y[8n+c8] = relu(feats[n] @ W_up[c8] + b_up), stored bf16
__global__ __launch_bounds__(256) void k_up(const ushort_t* __restrict__ featb,
    const ushort_t* __restrict__ wupf, const float* __restrict__ bup,
    ushort_t* __restrict__ y)
{
  int wave = threadIdx.x >> 6, lane = threadIdx.x & 63;
  int n0 = blockIdx.x*64 + wave*16;
  if (n0 >= NPARENT) return;
  int lp = lane & 15, hi = lane >> 4;
  const ushort_t* ar = featb + (size_t)(n0+lp)*64 + hi*8;
  bf16x8 a0 = *(const bf16x8*)(ar);
  bf16x8 a1 = *(const bf16x8*)(ar + 32);
  float bv[4];
  #pragma unroll
  for (int nt=0; nt<4; ++nt) bv[nt] = bup[nt*16+lp];
  for (int c8=0; c8<8; ++c8) {
    const ushort_t* wb = wupf + (size_t)c8*4096 + lane*8;
    f32x4 acc[4];
    #pragma unroll
    for (int nt=0;nt<4;++nt) acc[nt] = (f32x4){0.f,0.f,0.f,0.f};
    #pragma unroll
    for (int nt=0;nt<4;++nt)
      acc[nt] = __builtin_amdgcn_mfma_f32_16x16x32_bf16(a0, *(const bf16x8*)(wb + nt*512), acc[nt], 0,0,0);
    #pragma unroll
    for (int nt=0;nt<4;++nt)
      acc[nt] = __builtin_amdgcn_mfma_f32_16x16x32_bf16(a1, *(const bf16x8*)(wb + (4+nt)*512), acc[nt], 0,0,0);
    #pragma unroll
    for (int nt=0;nt<4;++nt) {
      #pragma unroll
      for (int j=0;j<4;++j) {
        int par = n0 + hi*4 + j;
        float v = acc[nt][j] + bv[nt];
        v = fmaxf(v, 0.f);
        y[(size_t)(par*8 + c8)*64 + nt*16 + lp] = f2bf(v);
      }
    }
  }
}

// sparse stride-1 conv as gather-GEMM. Wave = 64 rows x 64 cols, 27 offsets.
template<int RELU, typename OUT_T>
__global__ __launch_bounds__(256) void k_conv(const int* __restrict__ coords,
    const int* __restrict__ tbl, const ushort_t* __restrict__ fin,
    const ushort_t* __restrict__ wf, const float* __restrict__ bias,
    OUT_T* __restrict__ out)
{
  int wave = threadIdx.x >> 6, lane = threadIdx.x & 63;
  int m0 = blockIdx.x*256 + wave*64;
  int lp = lane & 15, hi = lane >> 4;

  // per-subtile row geometry: out coord v = 2*parent + child; v2 = v+2 so
  // neighbor parent (+1-shifted) = (v2+off)>>1, child bit parity = par^|off|
  int vx2[4], vy2[4], vz2[4], par[4];
  #pragma unroll
  for (int s=0;s<4;++s) {
    int r = m0 + s*16 + lp;
    int n = r >> 3, c = r & 7;
    int vx = 2*coords[3*n]   + ((c>>2)&1);
    int vy = 2*coords[3*n+1] + ((c>>1)&1);
    int vz = 2*coords[3*n+2] + (c&1);
    par[s] = ((vx&1)<<2) | ((vy&1)<<1) | (vz&1);
    vx2[s] = vx + 2; vy2[s] = vy + 2; vz2[s] = vz + 2;
  }

  f32x4 acc[4][4];
  #pragma unroll
  for (int s=0;s<4;++s)
    #pragma unroll
    for (int nt=0;nt<4;++nt) acc[s][nt] = (f32x4){0.f,0.f,0.f,0.f};

  const char* finl  = (const char*)fin + hi*16;   // lane's K-chunk within a row
  const char* wbase = (const char*)wf + lane*16;  // fragmentized weights

  auto nbr = [&](int ox, int oy, int oz, int s) -> uint32_t {
    int lin = (int)__umul24((unsigned)((vx2[s]+ox)>>1), 4356u)
            + (int)__umul24((unsigned)((vy2[s]+oy)>>1), 66u)
            + ((vz2[s]+oz)>>1);
    int pidx = tbl[lin];
    int xk = ((ox&1)<<2) | ((oy&1)<<1) | (oz&1);
    uint32_t off = (uint32_t)(pidx*8 + (par[s]^xk)) * 128u;
    return (pidx < 0) ? (uint32_t)ZIDX*128u : off;   // missing -> zero row
  };

  uint32_t aoff[4];
  #pragma unroll
  for (int s=0;s<4;++s) aoff[s] = nbr(-1,-1,-1,s);   // offset k=0

  #pragma unroll 1
  for (int k=0;k<27;++k) {
    const char* wk = wbase + k*8192;
    bf16x8 bfr[8];
    #pragma unroll
    for (int f=0;f<8;++f) bfr[f] = *(const bf16x8*)(wk + f*1024);
    bf16x8 a[4][2];
    #pragma unroll
    for (int s=0;s<4;++s) {
      a[s][0] = *(const bf16x8*)(finl + aoff[s]);
      a[s][1] = *(const bf16x8*)(finl + aoff[s] + 64);
    }
    if (k < 26) {   // prefetch next offset's table lookups under the MFMAs
      int k2 = k+1;
      int ox = k2/9 - 1, oy = (k2/3)%3 - 1, oz = k2%3 - 1;
      #pragma unroll
      for (int s=0;s<4;++s) aoff[s] = nbr(ox,oy,oz,s);
    }
    #pragma unroll
    for (int s=0;s<4;++s)
      #pragma unroll
      for (int nt=0;nt<4;++nt)
        acc[s][nt] = __builtin_amdgcn_mfma_f32_16x16x32_bf16(a[s][0], bfr[nt], acc[s][nt], 0,0,0);
    #pragma unroll
    for (int s=0;s<4;++s)
      #pragma unroll
      for (int nt=0;nt<4;++nt)
        acc[s][nt] = __builtin_amdgcn_mfma_f32_16x16x32_bf16(a[s][1], bfr[4+nt], acc[s][nt], 0,0,0);
  }

  float bv[4];
  #pragma unroll
  for (int nt=0;nt<4;++nt) bv[nt] = bias[nt*16+lp];
  #pragma unroll
  for (int s=0;s<4;++s) {
    #pragma unroll
    for (int nt=0;nt<4;++nt) {
      #pragma unroll
      for (int j=0;j<4;++j) {
        int row = m0 + s*16 + hi*4 + j;
        float v = acc[s][nt][j] + bv[nt];
        if (RELU) v = fmaxf(v, 0.f);
        size_t oi = (size_t)row*64 + nt*16 + lp;
        if constexpr (sizeof(OUT_T)==2) ((ushort_t*)out)[oi] = f2bf(v);
        else                            out[oi] = v;
      }
    }
  }
}

extern "C" void kernel_launch(void* const* d_in, const int* in_sizes, int n_in,
                              void* d_out, int out_size, void* d_ws, size_t ws_size,
                              hipStream_t stream) {
  const int*   coords = (const int*)d_in[0];
  const float* feats  = (const float*)d_in[1];
  const float* Wup    = (const float*)d_in[2];
  const float* bup    = (const float*)d_in[3];
  const float* W1     = (const float*)d_in[4];
  const float* b1     = (const float*)d_in[5];
  const float* W2     = (const float*)d_in[6];
  const float* b2     = (const float*)d_in[7];
  char* ws = (char*)d_ws;
  if (ws_size < WS_NEED) return;   // fail visibly rather than corrupt

  int*      tbl  = (int*)(ws + OFF_TABLE);
  ushort_t* y    = (ushort_t*)(ws + OFF_Y);
  ushort_t* z    = (ushort_t*)(ws + OFF_Z);
  ushort_t* fb   = (ushort_t*)(ws + OFF_FEATB);
  ushort_t* wupf = (ushort_t*)(ws + OFF_WUPF);
  ushort_t* w1f  = (ushort_t*)(ws + OFF_W1F);
  ushort_t* w2f  = (ushort_t*)(ws + OFF_W2F);

  hipMemsetAsync(tbl, 0xFF, (size_t)TBL_N*4, stream);
  k_zero<<<1,128,0,stream>>>(y, z);
  k_table<<<(NPARENT+255)/256,256,0,stream>>>(coords, tbl);
  k_feats_bf16<<<(NPARENT*16+255)/256,256,0,stream>>>((const float4*)feats, fb, NPARENT*16);
  k_wfrag<<<(8*4096+255)/256,256,0,stream>>>(Wup, wupf, 8*4096);
  k_wfrag<<<(27*4096+255)/256,256,0,stream>>>(W1, w1f, 27*4096);
  k_wfrag<<<(27*4096+255)/256,256,0,stream>>>(W2, w2f, 27*4096);
  k_up<<<(NPARENT+63)/64,256,0,stream>>>(fb, wupf, bup, y);
  k_conv<1, ushort_t><<<NOUT/256,256,0,stream>>>(coords, tbl, y,  w1f, b1, z);
  k_conv<0, float>   <<<NOUT/256,256,0,stream>>>(coords, tbl, z,  w2f, b2, (float*)d_out);
}